// Round 21
// baseline (592.451 us; speedup 1.0000x reference)
//
#include <hip/hip_runtime.h>
#include <cstdint>
#include <cstddef>

// ---------- problem constants ----------
#define DIM      1024
#define GROUP    16
#define LORA     20
#define NLAYERS  18
#define NBLOCKS  6
#define BATCH    8192
#define EPS      1e-5f

typedef __bf16 bf16_8 __attribute__((ext_vector_type(8)));
typedef __bf16 bf16_4 __attribute__((ext_vector_type(4)));
typedef float  f32x4  __attribute__((ext_vector_type(4)));

// ---------------------------------------------------------------------------
// Weight prep (R20, frozen): W = qw*scale + B@A -> single bf16.
// ---------------------------------------------------------------------------
__global__ __launch_bounds__(256, 3) void wprep_kernel(
    const int* __restrict__ qw, const float* __restrict__ sc,
    const float* __restrict__ la, const float* __restrict__ lb,
    __bf16* __restrict__ whi) {
  const int l  = blockIdx.x >> 7;
  const int og = (blockIdx.x >> 1) & 63;
  const int cg = blockIdx.x & 1;
  const int tid = threadIdx.x;
  const int tc = tid & 31;
  const int tr = tid >> 5;

  int4  q[2][2][2];
  float sv[2][2];
  size_t rowb[2];
#pragma unroll
  for (int u = 0; u < 2; ++u) {
    const int orow = og * 16 + tr * 2 + u;
    rowb[u] = ((size_t)l * DIM + orow) * DIM + cg * 512;
    const size_t scb = ((size_t)l * DIM + orow) * (DIM / GROUP) + cg * 32;
#pragma unroll
    for (int v = 0; v < 2; ++v) {
      const int c = v * 256 + tc * 8;
      q[u][v][0] = *(const int4*)&qw[rowb[u] + c];
      q[u][v][1] = *(const int4*)&qw[rowb[u] + c + 4];
      sv[u][v] = sc[scb + (c >> 4)];
    }
  }

  __shared__ __bf16 As[LORA * 512];
  __shared__ float  Bs[16 * LORA];

  const float* Abase = la + (size_t)l * LORA * DIM + cg * 512;
  const float* Bbase = lb + ((size_t)l * DIM + og * 16) * LORA;
  for (int i = tid; i < 16 * LORA; i += 256) Bs[i] = Bbase[i];
#pragma unroll
  for (int i = 0; i < 10; ++i) {
    const int f4 = i * 256 + tid;
    const float4 a = *(const float4*)(Abase + (size_t)(f4 >> 7) * DIM + (f4 & 127) * 4);
    const bf16_4 ab = {(__bf16)a.x, (__bf16)a.y, (__bf16)a.z, (__bf16)a.w};
    *(bf16_4*)&As[f4 * 4] = ab;
  }
  __syncthreads();

  float acc[2][16];
#pragma unroll
  for (int u = 0; u < 2; ++u)
#pragma unroll
    for (int v = 0; v < 2; ++v) {
      acc[u][v * 8 + 0] = q[u][v][0].x * sv[u][v];
      acc[u][v * 8 + 1] = q[u][v][0].y * sv[u][v];
      acc[u][v * 8 + 2] = q[u][v][0].z * sv[u][v];
      acc[u][v * 8 + 3] = q[u][v][0].w * sv[u][v];
      acc[u][v * 8 + 4] = q[u][v][1].x * sv[u][v];
      acc[u][v * 8 + 5] = q[u][v][1].y * sv[u][v];
      acc[u][v * 8 + 6] = q[u][v][1].z * sv[u][v];
      acc[u][v * 8 + 7] = q[u][v][1].w * sv[u][v];
    }

#pragma unroll 2
  for (int j = 0; j < LORA; ++j) {
    float af[2][8];
#pragma unroll
    for (int v = 0; v < 2; ++v) {
      const bf16_8 a8 = *(const bf16_8*)&As[j * 512 + v * 256 + tc * 8];
#pragma unroll
      for (int e = 0; e < 8; ++e) af[v][e] = (float)a8[e];
    }
#pragma unroll
    for (int u = 0; u < 2; ++u) {
      const float bj = Bs[(tr * 2 + u) * LORA + j];
#pragma unroll
      for (int v = 0; v < 2; ++v)
#pragma unroll
        for (int e = 0; e < 8; ++e) acc[u][v * 8 + e] += bj * af[v][e];
    }
  }

#pragma unroll
  for (int u = 0; u < 2; ++u) {
#pragma unroll
    for (int v = 0; v < 2; ++v) {
      bf16_8 hv;
#pragma unroll
      for (int e = 0; e < 8; ++e) hv[e] = (__bf16)acc[u][v * 8 + e];
      *(bf16_8*)&whi[rowb[u] + v * 256 + tc * 8] = hv;
    }
  }
}

// ---------------------------------------------------------------------------
// x prep: f32 -> single bf16
// ---------------------------------------------------------------------------
__global__ __launch_bounds__(256) void xprep_kernel(
    const float* __restrict__ x, __bf16* __restrict__ hi) {
  const size_t i = (size_t)blockIdx.x * 256 + threadIdx.x;
  const float4 v = ((const float4*)x)[i];
  const bf16_4 hv = {(__bf16)v.x, (__bf16)v.y, (__bf16)v.z, (__bf16)v.w};
  ((bf16_4*)hi)[i] = hv;
}

// ---------------------------------------------------------------------------
// 1-pass bf16 GEMM — 256x128 tile, BK=64, 512 thr, T2 XOR swizzle, 3 x 48KB
// ring, depth-2 counted vmcnt(6).  NEW (T3+T5, m201 mini-port — decisive test
// of the 8-phase gate now that T2+T4 prerequisites exist): each K-step is 8
// phases {1 stage-issue || w-frag ds_read (+x-frags at m==0) -> s_barrier ->
// setprio(1) 4 MFMA setprio(0) -> s_barrier}; vmcnt(6) once at phase 7.
// Waves slip between barriers: ds_read/stage of one wave overlaps MFMA of
// another, and setprio arbitrates for the MFMA wave (role-split now exists).
// Epilogue MODE: 0 relu->bf16; 1 +x residual; 2 +LN(Sprev) from stats.
// ---------------------------------------------------------------------------
#define GBUF    24576   // elems per buffer (48 KB)
#define GOFF_W  16384   // X 256x64 elems first, then W 128x64

__device__ __forceinline__ int swz_off(int row, int slot) {
  const int colb = (slot * 16) ^ ((row & 7) << 4);
  return (row * 128 + colb) >> 1;   // elem offset
}

template <int MODE>
__global__ __launch_bounds__(512, 1) void gemm1_kernel(
    const __bf16* __restrict__ X, const __bf16* __restrict__ Wh,
    const float* __restrict__ bias, __bf16* __restrict__ Oh,
    const float* __restrict__ Hin,          // MODE1: x;  MODE2: Sprev
    const float2* __restrict__ stats,       // MODE2: per-row {mean, inv}
    const float* __restrict__ lnw, const float* __restrict__ lnb,  // MODE2
    float* __restrict__ Sout) {
  __shared__ __bf16 smem[3 * GBUF];        // 144 KB

  const int tid  = threadIdx.x;
  const int lane = tid & 63;
  const int wv   = tid >> 6;
  const int wm   = wv >> 2;
  const int wn2  = wv & 3;
  const int xcd = blockIdx.x & 7;
  const int kk2 = blockIdx.x >> 3;
  const int tm  = xcd * 4 + (kk2 >> 3);
  const int tn  = kk2 & 7;
  const int rowX = tm * 256, rowW = tn * 128;

  const int lr   = lane & 15;
  const int slot = lane >> 4;

  int offX[4], offW[4];
#pragma unroll
  for (int n = 0; n < 4; ++n) offX[n] = swz_off(wn2 * 64 + n * 16 + lr, slot);
#pragma unroll
  for (int m = 0; m < 4; ++m) offW[m] = GOFF_W + swz_off(wm * 64 + m * 16 + lr, slot);

  f32x4 acc[4][4];
#pragma unroll
  for (int m = 0; m < 4; ++m)
#pragma unroll
    for (int n = 0; n < 4; ++n) acc[m][n] = f32x4{0.f, 0.f, 0.f, 0.f};

  // issue load idx (0..3 = X chunks, 4..5 = W chunks) for tile t
  auto stage_one = [&](int t, int idx) {
    __bf16* sb = smem + (t % 3) * GBUF;
    if (idx < 4) {
      const int D = idx * 8192 + tid * 16;
      const int row = D >> 7;
      const int colb = (D & 127) ^ ((row & 7) << 4);
      const __bf16* gp = X + (size_t)(rowX + row) * DIM + t * 64 + (colb >> 1);
      __builtin_amdgcn_global_load_lds(
          (const __attribute__((address_space(1))) void*)gp,
          (__attribute__((address_space(3))) void*)(sb + idx * 4096 + (tid >> 6) * 512),
          16, 0, 0);
    } else {
      const int i = idx - 4;
      const int D = i * 8192 + tid * 16;
      const int row = D >> 7;
      const int colb = (D & 127) ^ ((row & 7) << 4);
      const __bf16* gp = Wh + (size_t)(rowW + row) * DIM + t * 64 + (colb >> 1);
      __builtin_amdgcn_global_load_lds(
          (const __attribute__((address_space(1))) void*)gp,
          (__attribute__((address_space(3))) void*)(sb + GOFF_W + i * 4096 + (tid >> 6) * 512),
          16, 0, 0);
    }
  };
  auto stage_tile = [&](int t) {
#pragma unroll
    for (int idx = 0; idx < 6; ++idx) stage_one(t, idx);
  };

  // monolithic compute (tail steps)
  auto compute_tile = [&](int t) {
    const __bf16* buf = smem + (t % 3) * GBUF;
#pragma unroll
    for (int kk = 0; kk < 2; ++kk) {
      const int kx = kk * 32;
      bf16_8 xf[4];
#pragma unroll
      for (int n = 0; n < 4; ++n) xf[n] = *(const bf16_8*)&buf[offX[n] ^ kx];
#pragma unroll
      for (int m = 0; m < 4; ++m) {
        const bf16_8 w_h = *(const bf16_8*)&buf[offW[m] ^ kx];
#pragma unroll
        for (int n = 0; n < 4; ++n)
          acc[m][n] = __builtin_amdgcn_mfma_f32_16x16x32_bf16(w_h, xf[n], acc[m][n], 0, 0, 0);
      }
    }
  };

  // prologue: tiles 0,1 issued; vmcnt(6) -> tile 0 landed, tile 1 in flight
  stage_tile(0); stage_tile(1);
  asm volatile("s_waitcnt vmcnt(6)" ::: "memory");
  __builtin_amdgcn_s_barrier();

#pragma unroll 1
  for (int kt = 0; kt < 14; ++kt) {
    const __bf16* buf = smem + (kt % 3) * GBUF;
    bf16_8 xf[4];
#pragma unroll
    for (int p = 0; p < 8; ++p) {
      const int kk = p >> 2, m = p & 3;
      const int kx = kk * 32;
      if (p < 6) stage_one(kt + 2, p);     // 1 gload_lds issue per phase
      if (m == 0) {
#pragma unroll
        for (int n = 0; n < 4; ++n) xf[n] = *(const bf16_8*)&buf[offX[n] ^ kx];
      }
      const bf16_8 w_h = *(const bf16_8*)&buf[offW[m] ^ kx];
      if (p == 7)  // drain tile kt+1's 6 (oldest); kt+2's 6 stay in flight
        asm volatile("s_waitcnt vmcnt(6)" ::: "memory");
      __builtin_amdgcn_s_barrier();
      __builtin_amdgcn_s_setprio(1);
#pragma unroll
      for (int n = 0; n < 4; ++n)
        acc[m][n] = __builtin_amdgcn_mfma_f32_16x16x32_bf16(w_h, xf[n], acc[m][n], 0, 0, 0);
      __builtin_amdgcn_s_setprio(0);
      __builtin_amdgcn_s_barrier();
    }
  }
  compute_tile(14);
  asm volatile("s_waitcnt vmcnt(0)" ::: "memory");
  __builtin_amdgcn_s_barrier();
  compute_tile(15);

  // epilogue: D reg-quad = 4 consecutive features of one batch row
  const int g4 = slot * 4;
#pragma unroll
  for (int m = 0; m < 4; ++m) {
    const int feat = tn * 128 + wm * 64 + m * 16 + g4;
    const float4 bv = *(const float4*)&bias[feat];
    float4 wq, bq;
    if constexpr (MODE == 2) {
      wq = *(const float4*)&lnw[feat];
      bq = *(const float4*)&lnb[feat];
    }
#pragma unroll
    for (int n = 0; n < 4; ++n) {
      const int nb = tm * 256 + wn2 * 64 + n * 16 + lr;
      const size_t base = (size_t)nb * DIM + feat;
      float v0 = acc[m][n][0] + bv.x;
      float v1 = acc[m][n][1] + bv.y;
      float v2 = acc[m][n][2] + bv.z;
      float v3 = acc[m][n][3] + bv.w;
      if constexpr (MODE == 0) {
        const bf16_4 hv = {(__bf16)fmaxf(v0, 0.f), (__bf16)fmaxf(v1, 0.f),
                           (__bf16)fmaxf(v2, 0.f), (__bf16)fmaxf(v3, 0.f)};
        *(bf16_4*)&Oh[base] = hv;
      } else if constexpr (MODE == 1) {
        const float4 h = *(const float4*)&Hin[base];
        *(float4*)&Sout[base] = float4{v0 + h.x, v1 + h.y, v2 + h.z, v3 + h.w};
      } else {
        const float2 st = stats[nb];
        const float4 s = *(const float4*)&Hin[base];
        const float h0 = (s.x - st.x) * st.y * wq.x + bq.x;
        const float h1 = (s.y - st.x) * st.y * wq.y + bq.y;
        const float h2 = (s.z - st.x) * st.y * wq.z + bq.z;
        const float h3 = (s.w - st.x) * st.y * wq.w + bq.w;
        *(float4*)&Sout[base] = float4{v0 + h0, v1 + h1, v2 + h2, v3 + h3};
      }
    }
  }
}

// ---------------------------------------------------------------------------
// normcast: per-row stats {mean, inv} + bf16 LN output (next block's X).
// ---------------------------------------------------------------------------
__global__ __launch_bounds__(256) void normcast_kernel(
    const float* __restrict__ S, const float* __restrict__ w,
    const float* __restrict__ b, float2* __restrict__ stats,
    __bf16* __restrict__ phi) {
  const int row = blockIdx.x;
  const int tid = threadIdx.x;
  const int lane = tid & 63;
  const int wv = tid >> 6;
  const float4 v = ((const float4*)(S + (size_t)row * DIM))[tid];

  float s = v.x + v.y + v.z + v.w;
#pragma unroll
  for (int m = 32; m; m >>= 1) s += __shfl_xor(s, m, 64);
  __shared__ float red[8];
  if (lane == 0) red[wv] = s;
  __syncthreads();
  const float mean = (red[0] + red[1] + red[2] + red[3]) * (1.f / DIM);

  const float d0 = v.x - mean, d1 = v.y - mean, d2 = v.z - mean, d3 = v.w - mean;
  float q = d0 * d0 + d1 * d1 + d2 * d2 + d3 * d3;
#pragma unroll
  for (int m = 32; m; m >>= 1) q += __shfl_xor(q, m, 64);
  if (lane == 0) red[4 + wv] = q;
  __syncthreads();
  const float var = (red[4] + red[5] + red[6] + red[7]) * (1.f / DIM);
  const float inv = 1.f / sqrtf(var + EPS);

  if (tid == 0) stats[row] = float2{mean, inv};

  const float4 wv4 = ((const float4*)w)[tid];
  const float4 bv4 = ((const float4*)b)[tid];
  const bf16_4 hv = {(__bf16)(d0 * inv * wv4.x + bv4.x),
                     (__bf16)(d1 * inv * wv4.y + bv4.y),
                     (__bf16)(d2 * inv * wv4.z + bv4.z),
                     (__bf16)(d3 * inv * wv4.w + bv4.w)};
  ((bf16_4*)phi)[(size_t)row * (DIM / 4) + tid] = hv;
}

// ---------------------------------------------------------------------------
// launch
// ---------------------------------------------------------------------------
extern "C" void kernel_launch(void* const* d_in, const int* in_sizes, int n_in,
                              void* d_out, int out_size, void* d_ws, size_t ws_size,
                              hipStream_t stream) {
  const float* x   = (const float*)d_in[0];
  const int*   qw  = (const int*)d_in[1];
  const float* sc  = (const float*)d_in[2];
  const float* bias= (const float*)d_in[3];
  const float* la  = (const float*)d_in[4];
  const float* lb  = (const float*)d_in[5];
  const float* lnw = (const float*)d_in[6];
  const float* lnb = (const float*)d_in[7];
  float* out = (float*)d_out;
  char* ws = (char*)d_ws;

  // ws layout (bytes): WHI 36M | X0 16M | X1 16M | SA 32M | SB 32M | stats 64K
  __bf16* WHI = (__bf16*)(ws);
  __bf16* X0  = (__bf16*)(ws + 37748736);
  __bf16* X1  = (__bf16*)(ws + 54525952);
  float*  SA  = (float*)(ws + 71303168);
  float*  SB  = (float*)(ws + 104857600);
  float2* STT = (float2*)(ws + 138412032);
  (void)ws_size; (void)in_sizes; (void)n_in; (void)out_size;

  xprep_kernel<<<BATCH * DIM / (256 * 4), 256, 0, stream>>>(x, X0);
  wprep_kernel<<<NLAYERS * 128, 256, 0, stream>>>(qw, sc, la, lb, WHI);

  const dim3 ggrid(BATCH / 256 * (DIM / 128));          // 256 = 1 block/CU
  for (int blk = 0; blk < NBLOCKS; ++blk) {
    const int li = blk * 3;
    const size_t w0 = (size_t)li * DIM * DIM;
    const size_t w1 = (size_t)(li + 1) * DIM * DIM;
    const size_t w2 = (size_t)(li + 2) * DIM * DIM;
    float* Scur = (blk & 1) ? SB : SA;
    float* Sprev = (blk & 1) ? SA : SB;

    gemm1_kernel<0><<<ggrid, 512, 0, stream>>>(
        X0, WHI + w0, bias + (size_t)li * DIM, X1,
        nullptr, nullptr, nullptr, nullptr, nullptr);
    gemm1_kernel<0><<<ggrid, 512, 0, stream>>>(
        X1, WHI + w1, bias + (size_t)(li + 1) * DIM, X0,
        nullptr, nullptr, nullptr, nullptr, nullptr);
    float* sout = (blk == NBLOCKS - 1) ? out : Scur;
    if (blk == 0) {
      gemm1_kernel<1><<<ggrid, 512, 0, stream>>>(
          X0, WHI + w2, bias + (size_t)(li + 2) * DIM, nullptr,
          x, nullptr, nullptr, nullptr, sout);
    } else {
      gemm1_kernel<2><<<ggrid, 512, 0, stream>>>(
          X0, WHI + w2, bias + (size_t)(li + 2) * DIM, nullptr,
          Sprev, STT, lnw + (size_t)(blk - 1) * DIM, lnb + (size_t)(blk - 1) * DIM,
          sout);
    }
    if (blk < NBLOCKS - 1) {
      normcast_kernel<<<BATCH, 256, 0, stream>>>(
          Scur, lnw + (size_t)blk * DIM, lnb + (size_t)blk * DIM, STT, X0);
    }
  }
}

// Round 22
// 521.469 us; speedup vs baseline: 1.1361x; 1.1361x over previous
//
#include <hip/hip_runtime.h>
#include <cstdint>
#include <cstddef>

// ---------- problem constants ----------
#define DIM      1024
#define GROUP    16
#define LORA     20
#define NLAYERS  18
#define NBLOCKS  6
#define BATCH    8192
#define EPS      1e-5f

typedef __bf16 bf16_8 __attribute__((ext_vector_type(8)));
typedef __bf16 bf16_4 __attribute__((ext_vector_type(4)));
typedef float  f32x4  __attribute__((ext_vector_type(4)));

// ---------------------------------------------------------------------------
// Weight prep (R20, frozen): W = qw*scale + B@A -> single bf16.
// ---------------------------------------------------------------------------
__global__ __launch_bounds__(256, 3) void wprep_kernel(
    const int* __restrict__ qw, const float* __restrict__ sc,
    const float* __restrict__ la, const float* __restrict__ lb,
    __bf16* __restrict__ whi) {
  const int l  = blockIdx.x >> 7;
  const int og = (blockIdx.x >> 1) & 63;
  const int cg = blockIdx.x & 1;
  const int tid = threadIdx.x;
  const int tc = tid & 31;
  const int tr = tid >> 5;

  int4  q[2][2][2];
  float sv[2][2];
  size_t rowb[2];
#pragma unroll
  for (int u = 0; u < 2; ++u) {
    const int orow = og * 16 + tr * 2 + u;
    rowb[u] = ((size_t)l * DIM + orow) * DIM + cg * 512;
    const size_t scb = ((size_t)l * DIM + orow) * (DIM / GROUP) + cg * 32;
#pragma unroll
    for (int v = 0; v < 2; ++v) {
      const int c = v * 256 + tc * 8;
      q[u][v][0] = *(const int4*)&qw[rowb[u] + c];
      q[u][v][1] = *(const int4*)&qw[rowb[u] + c + 4];
      sv[u][v] = sc[scb + (c >> 4)];
    }
  }

  __shared__ __bf16 As[LORA * 512];
  __shared__ float  Bs[16 * LORA];

  const float* Abase = la + (size_t)l * LORA * DIM + cg * 512;
  const float* Bbase = lb + ((size_t)l * DIM + og * 16) * LORA;
  for (int i = tid; i < 16 * LORA; i += 256) Bs[i] = Bbase[i];
#pragma unroll
  for (int i = 0; i < 10; ++i) {
    const int f4 = i * 256 + tid;
    const float4 a = *(const float4*)(Abase + (size_t)(f4 >> 7) * DIM + (f4 & 127) * 4);
    const bf16_4 ab = {(__bf16)a.x, (__bf16)a.y, (__bf16)a.z, (__bf16)a.w};
    *(bf16_4*)&As[f4 * 4] = ab;
  }
  __syncthreads();

  float acc[2][16];
#pragma unroll
  for (int u = 0; u < 2; ++u)
#pragma unroll
    for (int v = 0; v < 2; ++v) {
      acc[u][v * 8 + 0] = q[u][v][0].x * sv[u][v];
      acc[u][v * 8 + 1] = q[u][v][0].y * sv[u][v];
      acc[u][v * 8 + 2] = q[u][v][0].z * sv[u][v];
      acc[u][v * 8 + 3] = q[u][v][0].w * sv[u][v];
      acc[u][v * 8 + 4] = q[u][v][1].x * sv[u][v];
      acc[u][v * 8 + 5] = q[u][v][1].y * sv[u][v];
      acc[u][v * 8 + 6] = q[u][v][1].z * sv[u][v];
      acc[u][v * 8 + 7] = q[u][v][1].w * sv[u][v];
    }

#pragma unroll 2
  for (int j = 0; j < LORA; ++j) {
    float af[2][8];
#pragma unroll
    for (int v = 0; v < 2; ++v) {
      const bf16_8 a8 = *(const bf16_8*)&As[j * 512 + v * 256 + tc * 8];
#pragma unroll
      for (int e = 0; e < 8; ++e) af[v][e] = (float)a8[e];
    }
#pragma unroll
    for (int u = 0; u < 2; ++u) {
      const float bj = Bs[(tr * 2 + u) * LORA + j];
#pragma unroll
      for (int v = 0; v < 2; ++v)
#pragma unroll
        for (int e = 0; e < 8; ++e) acc[u][v * 8 + e] += bj * af[v][e];
    }
  }

#pragma unroll
  for (int u = 0; u < 2; ++u) {
#pragma unroll
    for (int v = 0; v < 2; ++v) {
      bf16_8 hv;
#pragma unroll
      for (int e = 0; e < 8; ++e) hv[e] = (__bf16)acc[u][v * 8 + e];
      *(bf16_8*)&whi[rowb[u] + v * 256 + tc * 8] = hv;
    }
  }
}

// ---------------------------------------------------------------------------
// x prep: f32 -> single bf16
// ---------------------------------------------------------------------------
__global__ __launch_bounds__(256) void xprep_kernel(
    const float* __restrict__ x, __bf16* __restrict__ hi) {
  const size_t i = (size_t)blockIdx.x * 256 + threadIdx.x;
  const float4 v = ((const float4*)x)[i];
  const bf16_4 hv = {(__bf16)v.x, (__bf16)v.y, (__bf16)v.z, (__bf16)v.w};
  ((bf16_4*)hi)[i] = hv;
}

// ---------------------------------------------------------------------------
// 1-pass bf16 GEMM (R20, the measured optimum for this shape): 256x128 tile,
// BK=64, 512 thr, T2 XOR swizzle (inverse on global_load_lds source),
// 3 x 48KB ring, depth-2 counted vmcnt(6), monolithic 1-step rotation.
// (8-phase/T5 variants tested R4/R11/R21: all neutral-to-negative at this
// shape — phase granularity that fits costs more sync than it recovers.)
// Epilogue MODE: 0 relu->bf16; 1 +x residual; 2 +LN(Sprev) from stats.
// ---------------------------------------------------------------------------
#define GBUF    24576   // elems per buffer (48 KB)
#define GOFF_W  16384   // X 256x64 elems first, then W 128x64

__device__ __forceinline__ int swz_off(int row, int slot) {
  const int colb = (slot * 16) ^ ((row & 7) << 4);
  return (row * 128 + colb) >> 1;   // elem offset
}

template <int NISSUE>
__device__ __forceinline__ void stageR(const __bf16* __restrict__ g, int row0, int k0,
                                       __bf16* lds, int tid) {
#pragma unroll
  for (int i = 0; i < NISSUE; ++i) {
    const int D = i * 8192 + tid * 16;     // linear LDS byte in region
    const int row = D >> 7;                // 128 B per row (BK=64 bf16)
    const int colb = (D & 127) ^ ((row & 7) << 4);   // inverse swizzle on src
    const __bf16* gp = g + (size_t)(row0 + row) * DIM + k0 + (colb >> 1);
    __builtin_amdgcn_global_load_lds(
        (const __attribute__((address_space(1))) void*)gp,
        (__attribute__((address_space(3))) void*)(lds + i * 4096 + (tid >> 6) * 512), 16, 0, 0);
  }
}

template <int MODE>
__global__ __launch_bounds__(512, 1) void gemm1_kernel(
    const __bf16* __restrict__ X, const __bf16* __restrict__ Wh,
    const float* __restrict__ bias, __bf16* __restrict__ Oh,
    const float* __restrict__ Hin,          // MODE1: x;  MODE2: Sprev
    const float2* __restrict__ stats,       // MODE2: per-row {mean, inv}
    const float* __restrict__ lnw, const float* __restrict__ lnb,  // MODE2
    float* __restrict__ Sout) {
  __shared__ __bf16 smem[3 * GBUF];        // 144 KB

  const int tid  = threadIdx.x;
  const int lane = tid & 63;
  const int wv   = tid >> 6;
  const int wm   = wv >> 2;
  const int wn2  = wv & 3;
  const int xcd = blockIdx.x & 7;
  const int kk2 = blockIdx.x >> 3;
  const int tm  = xcd * 4 + (kk2 >> 3);
  const int tn  = kk2 & 7;
  const int rowX = tm * 256, rowW = tn * 128;

  const int lr   = lane & 15;
  const int slot = lane >> 4;

  int offX[4], offW[4];
#pragma unroll
  for (int n = 0; n < 4; ++n) offX[n] = swz_off(wn2 * 64 + n * 16 + lr, slot);
#pragma unroll
  for (int m = 0; m < 4; ++m) offW[m] = GOFF_W + swz_off(wm * 64 + m * 16 + lr, slot);

  f32x4 acc[4][4];
#pragma unroll
  for (int m = 0; m < 4; ++m)
#pragma unroll
    for (int n = 0; n < 4; ++n) acc[m][n] = f32x4{0.f, 0.f, 0.f, 0.f};

  auto stage_tile = [&](int t) {
    __bf16* sb = smem + (t % 3) * GBUF;
    stageR<4>(X,  rowX, t * 64, sb, tid);
    stageR<2>(Wh, rowW, t * 64, sb + GOFF_W, tid);
  };

  auto compute_tile = [&](int t) {
    const __bf16* buf = smem + (t % 3) * GBUF;
#pragma unroll
    for (int kk = 0; kk < 2; ++kk) {
      const int kx = kk * 32;              // elem XOR delta (byte 64)
      bf16_8 xf[4];
#pragma unroll
      for (int n = 0; n < 4; ++n) xf[n] = *(const bf16_8*)&buf[offX[n] ^ kx];
#pragma unroll
      for (int m = 0; m < 4; ++m) {
        const bf16_8 w_h = *(const bf16_8*)&buf[offW[m] ^ kx];
#pragma unroll
        for (int n = 0; n < 4; ++n)
          acc[m][n] = __builtin_amdgcn_mfma_f32_16x16x32_bf16(w_h, xf[n], acc[m][n], 0, 0, 0);
      }
    }
  };

  stage_tile(0); stage_tile(1);
  asm volatile("s_waitcnt vmcnt(6)" ::: "memory");
  __builtin_amdgcn_s_barrier();

#pragma unroll 1
  for (int kt = 0; kt < 14; ++kt) {
    stage_tile(kt + 2);
    compute_tile(kt);
    asm volatile("s_waitcnt vmcnt(6)" ::: "memory");
    __builtin_amdgcn_s_barrier();
  }
  compute_tile(14);
  asm volatile("s_waitcnt vmcnt(0)" ::: "memory");
  __builtin_amdgcn_s_barrier();
  compute_tile(15);

  // epilogue: D reg-quad = 4 consecutive features of one batch row
  const int g4 = slot * 4;
#pragma unroll
  for (int m = 0; m < 4; ++m) {
    const int feat = tn * 128 + wm * 64 + m * 16 + g4;
    const float4 bv = *(const float4*)&bias[feat];
    float4 wq, bq;
    if constexpr (MODE == 2) {
      wq = *(const float4*)&lnw[feat];
      bq = *(const float4*)&lnb[feat];
    }
#pragma unroll
    for (int n = 0; n < 4; ++n) {
      const int nb = tm * 256 + wn2 * 64 + n * 16 + lr;
      const size_t base = (size_t)nb * DIM + feat;
      float v0 = acc[m][n][0] + bv.x;
      float v1 = acc[m][n][1] + bv.y;
      float v2 = acc[m][n][2] + bv.z;
      float v3 = acc[m][n][3] + bv.w;
      if constexpr (MODE == 0) {
        const bf16_4 hv = {(__bf16)fmaxf(v0, 0.f), (__bf16)fmaxf(v1, 0.f),
                           (__bf16)fmaxf(v2, 0.f), (__bf16)fmaxf(v3, 0.f)};
        *(bf16_4*)&Oh[base] = hv;
      } else if constexpr (MODE == 1) {
        const float4 h = *(const float4*)&Hin[base];
        *(float4*)&Sout[base] = float4{v0 + h.x, v1 + h.y, v2 + h.z, v3 + h.w};
      } else {
        const float2 st = stats[nb];                   // {mean, inv}
        const float4 s = *(const float4*)&Hin[base];   // Sprev
        const float h0 = (s.x - st.x) * st.y * wq.x + bq.x;
        const float h1 = (s.y - st.x) * st.y * wq.y + bq.y;
        const float h2 = (s.z - st.x) * st.y * wq.z + bq.z;
        const float h3 = (s.w - st.x) * st.y * wq.w + bq.w;
        *(float4*)&Sout[base] = float4{v0 + h0, v1 + h1, v2 + h2, v3 + h3};
      }
    }
  }
}

// ---------------------------------------------------------------------------
// normcast: per-row stats {mean, inv} + bf16 LN output (next block's X).
// ---------------------------------------------------------------------------
__global__ __launch_bounds__(256) void normcast_kernel(
    const float* __restrict__ S, const float* __restrict__ w,
    const float* __restrict__ b, float2* __restrict__ stats,
    __bf16* __restrict__ phi) {
  const int row = blockIdx.x;
  const int tid = threadIdx.x;
  const int lane = tid & 63;
  const int wv = tid >> 6;
  const float4 v = ((const float4*)(S + (size_t)row * DIM))[tid];

  float s = v.x + v.y + v.z + v.w;
#pragma unroll
  for (int m = 32; m; m >>= 1) s += __shfl_xor(s, m, 64);
  __shared__ float red[8];
  if (lane == 0) red[wv] = s;
  __syncthreads();
  const float mean = (red[0] + red[1] + red[2] + red[3]) * (1.f / DIM);

  const float d0 = v.x - mean, d1 = v.y - mean, d2 = v.z - mean, d3 = v.w - mean;
  float q = d0 * d0 + d1 * d1 + d2 * d2 + d3 * d3;
#pragma unroll
  for (int m = 32; m; m >>= 1) q += __shfl_xor(q, m, 64);
  if (lane == 0) red[4 + wv] = q;
  __syncthreads();
  const float var = (red[4] + red[5] + red[6] + red[7]) * (1.f / DIM);
  const float inv = 1.f / sqrtf(var + EPS);

  if (tid == 0) stats[row] = float2{mean, inv};

  const float4 wv4 = ((const float4*)w)[tid];
  const float4 bv4 = ((const float4*)b)[tid];
  const bf16_4 hv = {(__bf16)(d0 * inv * wv4.x + bv4.x),
                     (__bf16)(d1 * inv * wv4.y + bv4.y),
                     (__bf16)(d2 * inv * wv4.z + bv4.z),
                     (__bf16)(d3 * inv * wv4.w + bv4.w)};
  ((bf16_4*)phi)[(size_t)row * (DIM / 4) + tid] = hv;
}

// ---------------------------------------------------------------------------
// launch
// ---------------------------------------------------------------------------
extern "C" void kernel_launch(void* const* d_in, const int* in_sizes, int n_in,
                              void* d_out, int out_size, void* d_ws, size_t ws_size,
                              hipStream_t stream) {
  const float* x   = (const float*)d_in[0];
  const int*   qw  = (const int*)d_in[1];
  const float* sc  = (const float*)d_in[2];
  const float* bias= (const float*)d_in[3];
  const float* la  = (const float*)d_in[4];
  const float* lb  = (const float*)d_in[5];
  const float* lnw = (const float*)d_in[6];
  const float* lnb = (const float*)d_in[7];
  float* out = (float*)d_out;
  char* ws = (char*)d_ws;

  // ws layout (bytes): WHI 36M | X0 16M | X1 16M | SA 32M | SB 32M | stats 64K
  __bf16* WHI = (__bf16*)(ws);
  __bf16* X0  = (__bf16*)(ws + 37748736);
  __bf16* X1  = (__bf16*)(ws + 54525952);
  float*  SA  = (float*)(ws + 71303168);
  float*  SB  = (float*)(ws + 104857600);
  float2* STT = (float2*)(ws + 138412032);
  (void)ws_size; (void)in_sizes; (void)n_in; (void)out_size;

  xprep_kernel<<<BATCH * DIM / (256 * 4), 256, 0, stream>>>(x, X0);
  wprep_kernel<<<NLAYERS * 128, 256, 0, stream>>>(qw, sc, la, lb, WHI);

  const dim3 ggrid(BATCH / 256 * (DIM / 128));          // 256 = 1 block/CU
  for (int blk = 0; blk < NBLOCKS; ++blk) {
    const int li = blk * 3;
    const size_t w0 = (size_t)li * DIM * DIM;
    const size_t w1 = (size_t)(li + 1) * DIM * DIM;
    const size_t w2 = (size_t)(li + 2) * DIM * DIM;
    float* Scur = (blk & 1) ? SB : SA;
    float* Sprev = (blk & 1) ? SA : SB;

    gemm1_kernel<0><<<ggrid, 512, 0, stream>>>(
        X0, WHI + w0, bias + (size_t)li * DIM, X1,
        nullptr, nullptr, nullptr, nullptr, nullptr);
    gemm1_kernel<0><<<ggrid, 512, 0, stream>>>(
        X1, WHI + w1, bias + (size_t)(li + 1) * DIM, X0,
        nullptr, nullptr, nullptr, nullptr, nullptr);
    float* sout = (blk == NBLOCKS - 1) ? out : Scur;
    if (blk == 0) {
      gemm1_kernel<1><<<ggrid, 512, 0, stream>>>(
          X0, WHI + w2, bias + (size_t)(li + 2) * DIM, nullptr,
          x, nullptr, nullptr, nullptr, sout);
    } else {
      gemm1_kernel<2><<<ggrid, 512, 0, stream>>>(
          X0, WHI + w2, bias + (size_t)(li + 2) * DIM, nullptr,
          Sprev, STT, lnw + (size_t)(blk - 1) * DIM, lnb + (size_t)(blk - 1) * DIM,
          sout);
    }
    if (blk < NBLOCKS - 1) {
      normcast_kernel<<<BATCH, 256, 0, stream>>>(
          Scur, lnw + (size_t)blk * DIM, lnb + (size_t)blk * DIM, STT, X0);
    }
  }
}